// Round 11
// baseline (753.575 us; speedup 1.0000x reference)
//
#include <hip/hip_runtime.h>

typedef unsigned short u16;
typedef __bf16 bf16x8_t __attribute__((ext_vector_type(8)));
typedef float f32x4_t __attribute__((ext_vector_type(4)));

__device__ __forceinline__ float bf2f(u16 u) {
    union { unsigned u; float f; } c; c.u = ((unsigned)u) << 16; return c.f;
}
__device__ __forceinline__ u16 f2bf(float f) {
    union { float f; unsigned u; } c; c.f = f;
    unsigned u = c.u;
    unsigned r = (u + 0x7FFFu + ((u >> 16) & 1u)) >> 16;
    return (u16)r;
}

// async global->LDS, 16B per lane. LDS dest is wave-uniform base + lane*16.
__device__ __forceinline__ void gld16(const u16* g, u16* l) {
    __builtin_amdgcn_global_load_lds(
        (const __attribute__((address_space(1))) unsigned*)g,
        (__attribute__((address_space(3))) unsigned*)l, 16, 0, 0);
}

// ---- LN1 + window partition: wave-per-row (barrier-free), 4 rows/block -----
__global__ __launch_bounds__(256) void ln1_window(
    const float* __restrict__ x, const float* __restrict__ w, const float* __restrict__ b,
    u16* __restrict__ out, int row0)
{
    int wv = threadIdx.x >> 6, lane = threadIdx.x & 63;
    int lrow = blockIdx.x * 4 + wv;
    int wr = row0 + lrow;
    int wb = wr / 196, t = wr % 196;
    int gh = ((wb % 25) / 5) * 14 + t / 14;
    int gw = (wb % 5) * 14 + t % 14;
    size_t orow = (size_t)lrow * 768;
    if (gh >= 64 || gw >= 64) {
        uint2 zz; zz.x = 0u; zz.y = 0u;
        for (int seg = 0; seg < 3; seg++)
            *(uint2*)&out[orow + seg * 256 + lane * 4] = zz;
        return;
    }
    size_t base = (size_t)(((wb / 25) * 64 + gh) * 64 + gw) * 768;
    f32x4_t v[3];
    float s = 0.f, sq = 0.f;
    for (int seg = 0; seg < 3; seg++) {
        v[seg] = *(const f32x4_t*)&x[base + seg * 256 + lane * 4];
        for (int j = 0; j < 4; j++) { s += v[seg][j]; sq += v[seg][j] * v[seg][j]; }
    }
    for (int o = 32; o > 0; o >>= 1) { s += __shfl_xor(s, o); sq += __shfl_xor(sq, o); }
    float mean = s * (1.0f / 768.0f);
    float var  = sq * (1.0f / 768.0f) - mean * mean;
    float inv  = rsqrtf(var + 1e-5f);
    for (int seg = 0; seg < 3; seg++) {
        f32x4_t w4 = *(const f32x4_t*)&w[seg * 256 + lane * 4];
        f32x4_t b4 = *(const f32x4_t*)&b[seg * 256 + lane * 4];
        u16 o0 = f2bf((v[seg][0] - mean) * inv * w4[0] + b4[0]);
        u16 o1 = f2bf((v[seg][1] - mean) * inv * w4[1] + b4[1]);
        u16 o2 = f2bf((v[seg][2] - mean) * inv * w4[2] + b4[2]);
        u16 o3 = f2bf((v[seg][3] - mean) * inv * w4[3] + b4[3]);
        uint2 pv; pv.x = (unsigned)o0 | ((unsigned)o1 << 16);
        pv.y = (unsigned)o2 | ((unsigned)o3 << 16);
        *(uint2*)&out[orow + seg * 256 + lane * 4] = pv;
    }
}

// ---- LN2: wave-per-row (barrier-free), 4 rows/block. grid Rm/4 -------------
__global__ __launch_bounds__(256) void ln2_chunk(
    const float* __restrict__ xin, const float* __restrict__ w, const float* __restrict__ b,
    u16* __restrict__ out)
{
    int wv = threadIdx.x >> 6, lane = threadIdx.x & 63;
    int row = blockIdx.x * 4 + wv;
    size_t base = (size_t)row * 768;
    f32x4_t v[3];
    float s = 0.f, sq = 0.f;
    for (int seg = 0; seg < 3; seg++) {
        v[seg] = *(const f32x4_t*)&xin[base + seg * 256 + lane * 4];
        for (int j = 0; j < 4; j++) { s += v[seg][j]; sq += v[seg][j] * v[seg][j]; }
    }
    for (int o = 32; o > 0; o >>= 1) { s += __shfl_xor(s, o); sq += __shfl_xor(sq, o); }
    float mean = s * (1.0f / 768.0f);
    float var  = sq * (1.0f / 768.0f) - mean * mean;
    float inv  = rsqrtf(var + 1e-5f);
    for (int seg = 0; seg < 3; seg++) {
        f32x4_t w4 = *(const f32x4_t*)&w[seg * 256 + lane * 4];
        f32x4_t b4 = *(const f32x4_t*)&b[seg * 256 + lane * 4];
        u16 o0 = f2bf((v[seg][0] - mean) * inv * w4[0] + b4[0]);
        u16 o1 = f2bf((v[seg][1] - mean) * inv * w4[1] + b4[1]);
        u16 o2 = f2bf((v[seg][2] - mean) * inv * w4[2] + b4[2]);
        u16 o3 = f2bf((v[seg][3] - mean) * inv * w4[3] + b4[3]);
        uint2 pv; pv.x = (unsigned)o0 | ((unsigned)o1 << 16);
        pv.y = (unsigned)o2 | ((unsigned)o3 << 16);
        *(uint2*)&out[base + seg * 256 + lane * 4] = pv;
    }
}

// ------------- weight transpose + cast: fp32 in[K][N] -> bf16 out[N][K] -----
__global__ __launch_bounds__(256) void transpose_wf(
    const float* __restrict__ in, u16* __restrict__ out, int K, int N)
{
    __shared__ u16 t[32][33];
    __shared__ u16 tt[32][32];   // row = n-local, 64B rows, 16B-aligned
    int n0 = blockIdx.x * 32, k0 = blockIdx.y * 32;
    int tx = threadIdx.x & 31, ty = threadIdx.x >> 5;
    for (int q = 0; q < 4; q++) {
        int k = k0 + ty + q * 8, n = n0 + tx;
        t[ty + q * 8][tx] = (k < K && n < N) ? f2bf(in[(size_t)k * N + n]) : (u16)0;
    }
    __syncthreads();
    for (int q = 0; q < 4; q++) tt[ty + q * 8][tx] = t[tx][ty + q * 8];
    __syncthreads();
    if (threadIdx.x < 128) {
        int r = threadIdx.x >> 2, c8 = (threadIdx.x & 3) << 3;
        int n = n0 + r, k = k0 + c8;
        if (n < N && k < K)
            *(uint4*)&out[(size_t)n * K + k] = *(const uint4*)&tt[r][c8];
    }
}

// --- rel tables -> bf16 combined matrix relT[64][64]: rows 0..26 = rel_h,
// rows 27..53 = rel_w, rows 54..63 = 0. Extended B-rows of the merged QK^T
// GEMM (B rows 196..249 = relT rows 0..53). ---------------------------------
__global__ __launch_bounds__(256) void build_relT(
    const float* __restrict__ rh, const float* __restrict__ rw, u16* __restrict__ out)
{
    int i = blockIdx.x * 256 + threadIdx.x;   // 16 blocks x 256 = 4096
    int r = i >> 6, c = i & 63;
    float v = (r < 27) ? rh[r * 64 + c] : (r < 54 ? rw[(r - 27) * 64 + c] : 0.f);
    out[i] = f2bf(v);
}

// ------- build V^T per (local window, head): vt[z][d][m], m padded to 224 ---
__global__ __launch_bounds__(256) void build_vt(
    const u16* __restrict__ qkvc, u16* __restrict__ vt)
{
    int z = blockIdx.x;
    int wb = z / 12, h = z % 12;
    __shared__ u16 t[64][232];   // 464B rows: 16B-aligned for uint4 reads
    int tid = threadIdx.x;
    for (int base = 0; base < 196; base += 4) {
        int m = base + (tid >> 6);
        int d = tid & 63;
        t[d][m] = qkvc[(size_t)(wb * 196 + m) * 2304 + 1536 + h * 64 + d];
    }
    for (int idx = tid; idx < 28 * 64; idx += 256) {
        int m = 196 + idx / 64, d = idx % 64;
        t[d][m] = 0;
    }
    __syncthreads();
    size_t ob = (size_t)z * 64 * 224;
    for (int idx = tid; idx < 64 * 28; idx += 256) {
        int d = idx / 28, c8 = (idx % 28) << 3;
        *(uint4*)&vt[ob + (size_t)d * 224 + c8] = *(const uint4*)&t[d][c8];
    }
}

// ------------- softmax v4: barrier-free, wave-per-row, 28 rows/block --------
// grid (7, Wc*12). S: [z][196][256] bf16 in place. Cols 0..195 = raw qk dots,
// cols 196..249 = rel dots (from the merged QK^T GEMM's extended B).
// bias(n,m) = S[n][209 + n/14 - m/14] + S[n][236 + n%14 - m%14].
// Bias cols are read BEFORE P overwrites cols 196..223 (program order,
// single wave owns each row). Writes P to cols 0..223 (196..223 -> 0).
__global__ __launch_bounds__(256) void softmax_rel2(
    u16* __restrict__ S)
{
    int z = blockIdx.y;
    int wv = threadIdx.x >> 6, lane = threadIdx.x & 63;
    int nbase = blockIdx.x * 28 + wv * 7;        // 7*28 = 196, all valid
    for (int i = 0; i < 7; i++) {
        int n = nbase + i;
        size_t srow = (size_t)z * 196 * 256 + (size_t)n * 256;
        int qh = n / 14, qw = n % 14;
        float s[4];
        for (int c = 0; c < 4; c++) {
            int m = c * 64 + lane;
            if (m < 196) {
                int kk = m / 14, jj = m % 14;
                float bh = bf2f(S[srow + 209 + qh - kk]);
                float bw = bf2f(S[srow + 236 + qw - jj]);
                s[c] = 0.125f * bf2f(S[srow + m]) + bh + bw;
            } else s[c] = -1e30f;
        }
        float mx = fmaxf(fmaxf(s[0], s[1]), fmaxf(s[2], s[3]));
        for (int o = 32; o > 0; o >>= 1) mx = fmaxf(mx, __shfl_xor(mx, o));
        float e[4], sm = 0.f;
        for (int c = 0; c < 4; c++) {
            int m = c * 64 + lane;
            e[c] = (m < 196) ? expf(s[c] - mx) : 0.f;
            sm += e[c];
        }
        for (int o = 32; o > 0; o >>= 1) sm += __shfl_xor(sm, o);
        float inv = 1.0f / sm;
        for (int c = 0; c < 4; c++) {
            int m = c * 64 + lane;
            if (m < 224) S[srow + m] = f2bf(e[c] * inv);
        }
    }
}

// LDS slot swizzle on the READ side. gload_lds writes LDS linearly; the
// matching permutation is applied to the GLOBAL source column slot
// (slot ^ (row>>1)&3), so LDS[row][s] holds global slot s^xr and the
// reader fetches global slot q at LDS[row][q^xr] == swz_off(row, q*8).
__device__ __forceinline__ int swz_off(int row, int kcElem) {
    return row * 32 + (kcElem ^ (((row >> 1) & 3) << 3));
}

// ---------------- NT-mode MFMA bf16 GEMM, 128x128 tile, BK=32 ----------------
// Mode-specialized K-loop (both variants hardware-proven r8/r9/r10):
//  LONG-K modes (0,3,4,5): 2-buffer + __syncthreads, 32 KB LDS, 4 blocks/CU.
//  SHORT-K modes (1,2; 2-7 K-steps): 3-buffer counted-vmcnt depth-2
//    pipeline, 48 KB LDS, 3 blocks/CU.
// MODE 0: qkv = lnw @ qkvT^T + bias              (bf16 out Cb)
// MODE 1: S = q [k | relT]^T per (window,head)   (bf16 out Cb, ld 256;
//          B rows 0..195 = k rows, 196..249 = relT rows — merged rel-bias GEMM)
// MODE 2: PV: P @ Vt^T -> qkvc q-slot (dead after mode 1)  (bf16, ld 2304)
// MODE 3: proj from qkvc q-slot — scatter; Cf[g] = x_fp32[g]+acc+bias (fp32)
// MODE 4: fc1 + bias + exact gelu                (bf16 out Cb)
// MODE 5: fc2 — Cf[idx] = xf[idx]+acc+bias       (fp32 d_out RMW)
template <int MODE>
__global__ __launch_bounds__(256, (MODE == 1 || MODE == 2) ? 3 : 4)
void gemm_nt(
    const u16* __restrict__ Aall, const u16* __restrict__ Ball,
    const float* __restrict__ bias, const float* xf,
    u16* __restrict__ Cb, float* Cf, int M, int row0)
{
    constexpr int BK = 32;
    constexpr bool DEEP = (MODE == 1 || MODE == 2);
    int N, K, lda, ldb;
    size_t aoff = 0, boff = 0, coff = 0;
    if constexpr (MODE == 0) { N = 2304; K = 768; lda = 768; ldb = 768; }
    else if constexpr (MODE == 1) {
        N = 250; K = 64; lda = 2304; ldb = 2304;
        int z = blockIdx.z;
        aoff = (size_t)(z / 12) * 196 * 2304 + (size_t)(z % 12) * 64;  // q
        boff = aoff + 768;                                             // k
        coff = (size_t)z * 196 * 256;
    } else if constexpr (MODE == 2) {
        N = 64; K = 224; lda = 256; ldb = 224;
        int z = blockIdx.z;
        aoff = (size_t)z * 196 * 256;                                  // P
        boff = (size_t)z * 64 * 224;                                   // V^T
        coff = (size_t)(z / 12) * 196 * 2304 + (size_t)(z % 12) * 64;  // q-slot
    } else if constexpr (MODE == 3) { N = 768; K = 768; lda = 2304; ldb = 768; }
    else if constexpr (MODE == 4) { N = 3072; K = 768; lda = 768; ldb = 768; }
    else { N = 768; K = 3072; lda = 3072; ldb = 3072; }

    // Staging buffers of 8192 u16 (As | Bs at +4096) each; epilogue reuses
    // [0, 8704 u16) as C staging.
    constexpr int NBUF = DEEP ? 3 : 2;
    __shared__ __align__(16) u16 smem[NBUF * 8192];

    int tid = threadIdx.x, wid = tid >> 6, lane = tid & 63;
    int quad = lane >> 4, l16 = lane & 15;

    // XCD-aware bijective block swizzle (m204) for single-z modes.
    int bx = blockIdx.x, by = blockIdx.y;
    if constexpr (MODE != 1 && MODE != 2) {
        int gX = gridDim.x;
        int nwg = gX * gridDim.y;
        int orig = by * gX + bx;
        int q = nwg >> 3, r = nwg & 7;
        int xcd = orig & 7, idx = orig >> 3;
        int wg = (xcd < r ? xcd * (q + 1) : r * (q + 1) + (xcd - r) * q) + idx;
        bx = wg % gX; by = wg / gX;
    }
    int m_tile = by * 128, n_tile = bx * 128;
    int wm0 = (wid >> 1) * 64, wn0 = (wid & 1) * 64;

    const u16* A = Aall + aoff;
    const u16* B = Ball + boff;
    const u16* rT = nullptr;
    if constexpr (MODE == 1) rT = (const u16*)xf;   // relT [64][64] bf16

    // staging: wave wid owns rows [wid*32, wid*32+32) of As and Bs.
    // 2 issues per operand; issue j: lane i -> lds row r0 + (i>>2), slot i&3.
    // global column slot pre-swizzled: (i&3) ^ ((row>>1)&3). rows clamped.
    const u16* gA[2]; const u16* gB[2];
    int loff[2];
    {
        int s = lane & 3, rofs = lane >> 2;
        for (int j = 0; j < 2; j++) {
            int r0 = wid * 32 + j * 16;
            int rr = r0 + rofs;
            int xr = (rr >> 1) & 3;
            int colo = ((s ^ xr) << 3);
            int am = m_tile + rr; if (am > M - 1) am = M - 1;
            int bn = n_tile + rr; if (bn > N - 1) bn = N - 1;
            gA[j] = A + (size_t)am * lda + colo;
            if constexpr (MODE == 1)
                gB[j] = (bn < 196) ? (B + (size_t)bn * 2304 + colo)
                                   : (rT + (size_t)(bn - 196) * 64 + colo);
            else
                gB[j] = B + (size_t)bn * ldb + colo;
            loff[j] = r0 * 32;
        }
    }

    f32x4_t acc[4][4];
    f32x4_t z4 = {0.f, 0.f, 0.f, 0.f};
    for (int mt = 0; mt < 4; mt++)
        for (int nt = 0; nt < 4; nt++) acc[mt][nt] = z4;

    if constexpr (!DEEP) {
        // --- r8-proven: 2-buffer, one __syncthreads per K-step ---
        for (int j = 0; j < 2; j++) {
            gld16(gA[j], smem + loff[j]);
            gld16(gB[j], smem + 4096 + loff[j]);
        }
        int cur = 0;
        for (int k0 = 0; k0 < K; k0 += BK) {
            __syncthreads();   // drains tile-k loads; waves done reading buf^1
            int boffc = cur << 13;
            if (k0 + BK < K) {
                int boffn = boffc ^ 8192;
                for (int j = 0; j < 2; j++) {
                    gld16(gA[j] + k0 + BK, smem + boffn + loff[j]);
                    gld16(gB[j] + k0 + BK, smem + boffn + 4096 + loff[j]);
                }
            }
            const u16* Ac = smem + boffc;
            const u16* Bc = smem + boffc + 4096;
            bf16x8_t af[4], bfv[4];
            for (int t = 0; t < 4; t++) {
                int ar = wm0 + t * 16 + l16;
                int br = wn0 + t * 16 + l16;
                af[t]  = *(const bf16x8_t*)&Ac[swz_off(ar, quad * 8)];
                bfv[t] = *(const bf16x8_t*)&Bc[swz_off(br, quad * 8)];
            }
            for (int mt = 0; mt < 4; mt++)
                for (int nt = 0; nt < 4; nt++)
                    acc[mt][nt] = __builtin_amdgcn_mfma_f32_16x16x32_bf16(
                        af[mt], bfv[nt], acc[mt][nt], 0, 0, 0);
            cur ^= 1;
        }
    } else {
        // --- r9-proven: 3-buffer counted-vmcnt depth-2 pipeline ---
        int nsteps = K / BK;   // 2..7 for DEEP modes
        for (int j = 0; j < 2; j++) {
            gld16(gA[j], smem + loff[j]);
            gld16(gB[j], smem + 4096 + loff[j]);
        }
        for (int j = 0; j < 2; j++) {
            gld16(gA[j] + BK, smem + 8192 + loff[j]);
            gld16(gB[j] + BK, smem + 12288 + loff[j]);
        }
        int cur = 0;
        for (int k = 0; k < nsteps; k++) {
            if (k + 1 < nsteps) {
                asm volatile("s_waitcnt vmcnt(4)" ::: "memory");
            } else {
                asm volatile("s_waitcnt vmcnt(0)" ::: "memory");
            }
            __builtin_amdgcn_sched_barrier(0);
            __builtin_amdgcn_s_barrier();
            __builtin_amdgcn_sched_barrier(0);
            if (k + 2 < nsteps) {
                int nb = cur + 2; if (nb >= 3) nb -= 3;
                u16* dst = smem + nb * 8192;
                int kn = (k + 2) * BK;
                for (int j = 0; j < 2; j++) {
                    gld16(gA[j] + kn, dst + loff[j]);
                    gld16(gB[j] + kn, dst + 4096 + loff[j]);
                }
            }
            const u16* Ac = smem + cur * 8192;
            const u16* Bc = Ac + 4096;
            bf16x8_t af[4], bfv[4];
            for (int t = 0; t < 4; t++) {
                int ar = wm0 + t * 16 + l16;
                int br = wn0 + t * 16 + l16;
                af[t]  = *(const bf16x8_t*)&Ac[swz_off(ar, quad * 8)];
                bfv[t] = *(const bf16x8_t*)&Bc[swz_off(br, quad * 8)];
            }
            for (int mt = 0; mt < 4; mt++)
                for (int nt = 0; nt < 4; nt++)
                    acc[mt][nt] = __builtin_amdgcn_mfma_f32_16x16x32_bf16(
                        af[mt], bfv[nt], acc[mt][nt], 0, 0, 0);
            cur++; if (cur >= 3) cur -= 3;
        }
    }

    // ---- epilogue (C/D frag layout: col=lane&15, row=quad*4+reg) ----
    if constexpr (MODE == 0 || MODE == 1 || MODE == 2 || MODE == 4) {
        u16* Cs = smem;   // [64][136] per half
        int ldc = (MODE == 0) ? 2304 : (MODE == 1) ? 256 : (MODE == 2) ? 2304 : 3072;
        int colmax = (MODE == 1) ? 256 : N;   // mode-1: junk cols 250..255 unread
        for (int half = 0; half < 2; half++) {
            __syncthreads();   // K-loop reads (or prev half) done
            if ((wm0 >> 6) == half) {
                for (int mt = 0; mt < 4; mt++) {
                    int rl = mt * 16 + quad * 4;
                    for (int nt = 0; nt < 4; nt++) {
                        int cl = wn0 + nt * 16 + l16;
                        int col = n_tile + cl;
                        for (int rg = 0; rg < 4; rg++) {
                            float v = acc[mt][nt][rg];
                            u16 o;
                            if constexpr (MODE == 0) o = f2bf(v + bias[col]);
                            else if constexpr (MODE == 4) {
                                float g = v + bias[col];
                                o = f2bf(0.5f * g * (1.0f + erff(g * 0.70710678118f)));
                            } else o = f2bf(v);
                            Cs[(rl + rg) * 136 + cl] = o;
                        }
                    }
                }
            }
            __syncthreads();
            for (int it = 0; it < 4; it++) {
                int chunk = tid + it * 256;
                int r = chunk >> 4, c8 = (chunk & 15) << 3;
                int grow = m_tile + half * 64 + r, gcol = n_tile + c8;
                if (grow >= M || gcol >= colmax) continue;
                *(uint4*)&Cb[coff + (size_t)grow * ldc + gcol] =
                    *(const uint4*)&Cs[r * 136 + c8];
            }
        }
    } else {
        // fp32 RMW modes (3, 5): four 32-row quarters through LDS
        float* Cfs = (float*)smem;   // [32][132]
        for (int q = 0; q < 4; q++) {
            __syncthreads();
            if ((wm0 >> 6) == (q >> 1)) {
                for (int mt2 = 0; mt2 < 2; mt2++) {
                    int mt = (q & 1) * 2 + mt2;
                    int rloc = mt2 * 16 + quad * 4;
                    for (int nt = 0; nt < 4; nt++) {
                        int cl = wn0 + nt * 16 + l16;
                        for (int rg = 0; rg < 4; rg++)
                            Cfs[(rloc + rg) * 132 + cl] = acc[mt][nt][rg];
                    }
                }
            }
            __syncthreads();
            for (int it = 0; it < 4; it++) {
                int chunk = tid + it * 256;
                int r = chunk >> 5, c4 = (chunk & 31) << 2;
                int grow = m_tile + q * 32 + r;
                int gcol = n_tile + c4;
                if (grow >= M || gcol >= N) continue;
                f32x4_t v4 = *(const f32x4_t*)&Cfs[r * 132 + c4];
                f32x4_t b4 = *(const f32x4_t*)&bias[gcol];
                if constexpr (MODE == 5) {
                    size_t idx = (size_t)(row0 + grow) * 768 + gcol;
                    f32x4_t x4 = *(const f32x4_t*)&xf[idx];
                    f32x4_t o4;
                    for (int j = 0; j < 4; j++) o4[j] = v4[j] + x4[j] + b4[j];
                    *(f32x4_t*)&Cf[idx] = o4;
                } else {
                    int wr = row0 + grow;
                    int wb2 = wr / 196, t2 = wr % 196;
                    int gh = ((wb2 % 25) / 5) * 14 + t2 / 14;
                    int gw = (wb2 % 5) * 14 + t2 % 14;
                    if (gh < 64 && gw < 64) {
                        size_t g = (size_t)(((wb2 / 25) * 64 + gh) * 64 + gw) * 768 + gcol;
                        f32x4_t x4 = *(const f32x4_t*)&xf[g];
                        f32x4_t o4;
                        for (int j = 0; j < 4; j++) o4[j] = v4[j] + x4[j] + b4[j];
                        *(f32x4_t*)&Cf[g] = o4;
                    }
                }
            }
        }
    }
}

extern "C" void kernel_launch(void* const* d_in, const int* in_sizes, int n_in,
                              void* d_out, int out_size, void* d_ws, size_t ws_size,
                              hipStream_t stream)
{
    (void)in_sizes; (void)n_in; (void)out_size;
    const float* x      = (const float*)d_in[0];
    const float* ln1_w  = (const float*)d_in[1];
    const float* ln1_b  = (const float*)d_in[2];
    const float* qkv_w  = (const float*)d_in[3];
    const float* qkv_b  = (const float*)d_in[4];
    const float* proj_w = (const float*)d_in[5];
    const float* proj_b = (const float*)d_in[6];
    const float* rel_h  = (const float*)d_in[7];
    const float* rel_w  = (const float*)d_in[8];
    const float* ln2_w  = (const float*)d_in[9];
    const float* ln2_b  = (const float*)d_in[10];
    const float* fc1_w  = (const float*)d_in[11];
    const float* fc1_b  = (const float*)d_in[12];
    const float* fc2_w  = (const float*)d_in[13];
    const float* fc2_b  = (const float*)d_in[14];

    // ---- ws layout: weights always at base, scratch above ----
    const size_t WT = 14155776ull + 8192ull;   // 13.5 MB weights + relT (8 KB)
    char* ws = (char*)d_ws;
    u16* qkvT  = (u16*)ws;
    u16* projT = qkvT + 2304 * 768;
    u16* fc1T  = projT + 768 * 768;
    u16* fc2T  = fc1T + 3072 * 768;
    u16* relT  = fc2T + 3072 * 768;            // [64][64] bf16
    char* scratch = ws + WT;
    size_t avail = (ws_size > WT) ? (ws_size - WT) : 0;

    // per-window: lnw 301056 + qkv 903168 + S 1204224 (ld 256) + vt 344064
    //           = 2752512  (attn output lives in qkvc's dead q-slot; no G2)
    const size_t perW = 2752512ull;
    static const int wc_cand[8] = {100, 50, 25, 20, 10, 5, 2, 1};
    int Wc = 1;
    for (int i = 0; i < 8; i++) {
        if ((size_t)wc_cand[i] * perW <= avail) { Wc = wc_cand[i]; break; }
    }
    static const int rm_cand[8] = {16384, 8192, 4096, 2048, 1024, 512, 256, 128};
    int Rm = 128;
    for (int i = 0; i < 8; i++) {
        if ((size_t)rm_cand[i] * 7680ull <= avail) { Rm = rm_cand[i]; break; }
    }

    u16* lnwc  = (u16*)scratch;
    u16* qkvc  = (u16*)(scratch + (size_t)Wc * 301056ull);
    u16* Sc    = (u16*)(scratch + (size_t)Wc * 1204224ull);
    u16* vtc   = (u16*)(scratch + (size_t)Wc * 2408448ull);
    u16* hbuf  = (u16*)scratch;                               // MLP overlays
    u16* xn2c  = (u16*)(scratch + (size_t)Rm * 6144ull);
    float* dout = (float*)d_out;                              // x1 (fp32)

    transpose_wf<<<dim3(72, 24), 256, 0, stream>>>(qkv_w, qkvT, 768, 2304);
    transpose_wf<<<dim3(24, 24), 256, 0, stream>>>(proj_w, projT, 768, 768);
    transpose_wf<<<dim3(96, 24), 256, 0, stream>>>(fc1_w, fc1T, 768, 3072);
    transpose_wf<<<dim3(24, 96), 256, 0, stream>>>(fc2_w, fc2T, 3072, 768);
    build_relT<<<16, 256, 0, stream>>>(rel_h, rel_w, relT);

    int nch = 100 / Wc;
    int rows = Wc * 196;
    int gy = (rows + 127) / 128;
    for (int c = 0; c < nch; c++) {
        int r0 = c * rows;
        ln1_window<<<rows / 4, 256, 0, stream>>>(x, ln1_w, ln1_b, lnwc, r0);
        gemm_nt<0><<<dim3(18, gy), 256, 0, stream>>>(
            lnwc, qkvT, qkv_b, nullptr, qkvc, nullptr, rows, 0);
        gemm_nt<1><<<dim3(2, 2, Wc * 12), 256, 0, stream>>>(
            qkvc, qkvc, nullptr, (const float*)relT, Sc, nullptr, 196, 0);
        build_vt<<<Wc * 12, 256, 0, stream>>>(qkvc, vtc);
        softmax_rel2<<<dim3(7, Wc * 12), 256, 0, stream>>>(Sc);
        gemm_nt<2><<<dim3(1, 2, Wc * 12), 256, 0, stream>>>(
            Sc, vtc, nullptr, nullptr, qkvc, nullptr, 196, 0);
        gemm_nt<3><<<dim3(6, gy), 256, 0, stream>>>(
            qkvc, projT, proj_b, x, nullptr, dout, rows, r0);
    }

    int nm = 16384 / Rm;
    for (int c = 0; c < nm; c++) {
        int r0 = c * Rm;
        ln2_chunk<<<Rm / 4, 256, 0, stream>>>(dout + (size_t)r0 * 768, ln2_w, ln2_b, xn2c);
        gemm_nt<4><<<dim3(24, Rm / 128), 256, 0, stream>>>(
            xn2c, fc1T, fc1_b, nullptr, hbuf, nullptr, Rm, 0);
        gemm_nt<5><<<dim3(6, Rm / 128), 256, 0, stream>>>(
            hbuf, fc2T, fc2_b, dout, nullptr, dout, Rm, r0);
    }
}

// Round 12
// 708.474 us; speedup vs baseline: 1.0637x; 1.0637x over previous
//
#include <hip/hip_runtime.h>

typedef unsigned short u16;
typedef __bf16 bf16x8_t __attribute__((ext_vector_type(8)));
typedef float f32x4_t __attribute__((ext_vector_type(4)));

__device__ __forceinline__ float bf2f(u16 u) {
    union { unsigned u; float f; } c; c.u = ((unsigned)u) << 16; return c.f;
}
__device__ __forceinline__ u16 f2bf(float f) {
    union { float f; unsigned u; } c; c.f = f;
    unsigned u = c.u;
    unsigned r = (u + 0x7FFFu + ((u >> 16) & 1u)) >> 16;
    return (u16)r;
}

// async global->LDS, 16B per lane. LDS dest is wave-uniform base + lane*16.
__device__ __forceinline__ void gld16(const u16* g, u16* l) {
    __builtin_amdgcn_global_load_lds(
        (const __attribute__((address_space(1))) unsigned*)g,
        (__attribute__((address_space(3))) unsigned*)l, 16, 0, 0);
}

// ---- LN1 + window partition: wave-per-row (barrier-free), 4 rows/block -----
__global__ __launch_bounds__(256) void ln1_window(
    const float* __restrict__ x, const float* __restrict__ w, const float* __restrict__ b,
    u16* __restrict__ out, int row0)
{
    int wv = threadIdx.x >> 6, lane = threadIdx.x & 63;
    int lrow = blockIdx.x * 4 + wv;
    int wr = row0 + lrow;
    int wb = wr / 196, t = wr % 196;
    int gh = ((wb % 25) / 5) * 14 + t / 14;
    int gw = (wb % 5) * 14 + t % 14;
    size_t orow = (size_t)lrow * 768;
    if (gh >= 64 || gw >= 64) {
        uint2 zz; zz.x = 0u; zz.y = 0u;
        for (int seg = 0; seg < 3; seg++)
            *(uint2*)&out[orow + seg * 256 + lane * 4] = zz;
        return;
    }
    size_t base = (size_t)(((wb / 25) * 64 + gh) * 64 + gw) * 768;
    f32x4_t v[3];
    float s = 0.f, sq = 0.f;
    for (int seg = 0; seg < 3; seg++) {
        v[seg] = *(const f32x4_t*)&x[base + seg * 256 + lane * 4];
        for (int j = 0; j < 4; j++) { s += v[seg][j]; sq += v[seg][j] * v[seg][j]; }
    }
    for (int o = 32; o > 0; o >>= 1) { s += __shfl_xor(s, o); sq += __shfl_xor(sq, o); }
    float mean = s * (1.0f / 768.0f);
    float var  = sq * (1.0f / 768.0f) - mean * mean;
    float inv  = rsqrtf(var + 1e-5f);
    for (int seg = 0; seg < 3; seg++) {
        f32x4_t w4 = *(const f32x4_t*)&w[seg * 256 + lane * 4];
        f32x4_t b4 = *(const f32x4_t*)&b[seg * 256 + lane * 4];
        u16 o0 = f2bf((v[seg][0] - mean) * inv * w4[0] + b4[0]);
        u16 o1 = f2bf((v[seg][1] - mean) * inv * w4[1] + b4[1]);
        u16 o2 = f2bf((v[seg][2] - mean) * inv * w4[2] + b4[2]);
        u16 o3 = f2bf((v[seg][3] - mean) * inv * w4[3] + b4[3]);
        uint2 pv; pv.x = (unsigned)o0 | ((unsigned)o1 << 16);
        pv.y = (unsigned)o2 | ((unsigned)o3 << 16);
        *(uint2*)&out[orow + seg * 256 + lane * 4] = pv;
    }
}

// ---- LN2: wave-per-row (barrier-free), 4 rows/block. grid Rm/4 -------------
__global__ __launch_bounds__(256) void ln2_chunk(
    const float* __restrict__ xin, const float* __restrict__ w, const float* __restrict__ b,
    u16* __restrict__ out)
{
    int wv = threadIdx.x >> 6, lane = threadIdx.x & 63;
    int row = blockIdx.x * 4 + wv;
    size_t base = (size_t)row * 768;
    f32x4_t v[3];
    float s = 0.f, sq = 0.f;
    for (int seg = 0; seg < 3; seg++) {
        v[seg] = *(const f32x4_t*)&xin[base + seg * 256 + lane * 4];
        for (int j = 0; j < 4; j++) { s += v[seg][j]; sq += v[seg][j] * v[seg][j]; }
    }
    for (int o = 32; o > 0; o >>= 1) { s += __shfl_xor(s, o); sq += __shfl_xor(sq, o); }
    float mean = s * (1.0f / 768.0f);
    float var  = sq * (1.0f / 768.0f) - mean * mean;
    float inv  = rsqrtf(var + 1e-5f);
    for (int seg = 0; seg < 3; seg++) {
        f32x4_t w4 = *(const f32x4_t*)&w[seg * 256 + lane * 4];
        f32x4_t b4 = *(const f32x4_t*)&b[seg * 256 + lane * 4];
        u16 o0 = f2bf((v[seg][0] - mean) * inv * w4[0] + b4[0]);
        u16 o1 = f2bf((v[seg][1] - mean) * inv * w4[1] + b4[1]);
        u16 o2 = f2bf((v[seg][2] - mean) * inv * w4[2] + b4[2]);
        u16 o3 = f2bf((v[seg][3] - mean) * inv * w4[3] + b4[3]);
        uint2 pv; pv.x = (unsigned)o0 | ((unsigned)o1 << 16);
        pv.y = (unsigned)o2 | ((unsigned)o3 << 16);
        *(uint2*)&out[base + seg * 256 + lane * 4] = pv;
    }
}

// ------------- weight transpose + cast: fp32 in[K][N] -> bf16 out[N][K] -----
__global__ __launch_bounds__(256) void transpose_wf(
    const float* __restrict__ in, u16* __restrict__ out, int K, int N)
{
    __shared__ u16 t[32][33];
    __shared__ u16 tt[32][32];   // row = n-local, 64B rows, 16B-aligned
    int n0 = blockIdx.x * 32, k0 = blockIdx.y * 32;
    int tx = threadIdx.x & 31, ty = threadIdx.x >> 5;
    for (int q = 0; q < 4; q++) {
        int k = k0 + ty + q * 8, n = n0 + tx;
        t[ty + q * 8][tx] = (k < K && n < N) ? f2bf(in[(size_t)k * N + n]) : (u16)0;
    }
    __syncthreads();
    for (int q = 0; q < 4; q++) tt[ty + q * 8][tx] = t[tx][ty + q * 8];
    __syncthreads();
    if (threadIdx.x < 128) {
        int r = threadIdx.x >> 2, c8 = (threadIdx.x & 3) << 3;
        int n = n0 + r, k = k0 + c8;
        if (n < N && k < K)
            *(uint4*)&out[(size_t)n * K + k] = *(const uint4*)&tt[r][c8];
    }
}

// --- rel tables -> bf16 combined matrix relT[64][64]: rows 0..26 = rel_h,
// rows 27..53 = rel_w, rows 54..63 = 0. Extended B-rows of the merged QK^T
// GEMM (B rows 196..249 = relT rows 0..53). ---------------------------------
__global__ __launch_bounds__(256) void build_relT(
    const float* __restrict__ rh, const float* __restrict__ rw, u16* __restrict__ out)
{
    int i = blockIdx.x * 256 + threadIdx.x;   // 16 blocks x 256 = 4096
    int r = i >> 6, c = i & 63;
    float v = (r < 27) ? rh[r * 64 + c] : (r < 54 ? rw[(r - 27) * 64 + c] : 0.f);
    out[i] = f2bf(v);
}

// ------- build V^T per (local window, head): vt[z][d][m], m padded to 224 ---
__global__ __launch_bounds__(256) void build_vt(
    const u16* __restrict__ qkvc, u16* __restrict__ vt)
{
    int z = blockIdx.x;
    int wb = z / 12, h = z % 12;
    __shared__ u16 t[64][232];   // 464B rows: 16B-aligned for uint4 reads
    int tid = threadIdx.x;
    for (int base = 0; base < 196; base += 4) {
        int m = base + (tid >> 6);
        int d = tid & 63;
        t[d][m] = qkvc[(size_t)(wb * 196 + m) * 2304 + 1536 + h * 64 + d];
    }
    for (int idx = tid; idx < 28 * 64; idx += 256) {
        int m = 196 + idx / 64, d = idx % 64;
        t[d][m] = 0;
    }
    __syncthreads();
    size_t ob = (size_t)z * 64 * 224;
    for (int idx = tid; idx < 64 * 28; idx += 256) {
        int d = idx / 28, c8 = (idx % 28) << 3;
        *(uint4*)&vt[ob + (size_t)d * 224 + c8] = *(const uint4*)&t[d][c8];
    }
}

// ------------- softmax v4: barrier-free, wave-per-row, 28 rows/block --------
// grid (7, Wc*12). S: [z][196][256] bf16 in place. Cols 0..195 = raw qk dots,
// cols 196..249 = rel dots (from the merged QK^T GEMM's extended B).
// bias(n,m) = S[n][209 + n/14 - m/14] + S[n][236 + n%14 - m%14].
// Bias cols are read BEFORE P overwrites cols 196..223 (program order,
// single wave owns each row). Writes P to cols 0..223 (196..223 -> 0).
__global__ __launch_bounds__(256) void softmax_rel2(
    u16* __restrict__ S)
{
    int z = blockIdx.y;
    int wv = threadIdx.x >> 6, lane = threadIdx.x & 63;
    int nbase = blockIdx.x * 28 + wv * 7;        // 7*28 = 196, all valid
    for (int i = 0; i < 7; i++) {
        int n = nbase + i;
        size_t srow = (size_t)z * 196 * 256 + (size_t)n * 256;
        int qh = n / 14, qw = n % 14;
        float s[4];
        for (int c = 0; c < 4; c++) {
            int m = c * 64 + lane;
            if (m < 196) {
                int kk = m / 14, jj = m % 14;
                float bh = bf2f(S[srow + 209 + qh - kk]);
                float bw = bf2f(S[srow + 236 + qw - jj]);
                s[c] = 0.125f * bf2f(S[srow + m]) + bh + bw;
            } else s[c] = -1e30f;
        }
        float mx = fmaxf(fmaxf(s[0], s[1]), fmaxf(s[2], s[3]));
        for (int o = 32; o > 0; o >>= 1) mx = fmaxf(mx, __shfl_xor(mx, o));
        float e[4], sm = 0.f;
        for (int c = 0; c < 4; c++) {
            int m = c * 64 + lane;
            e[c] = (m < 196) ? expf(s[c] - mx) : 0.f;
            sm += e[c];
        }
        for (int o = 32; o > 0; o >>= 1) sm += __shfl_xor(sm, o);
        float inv = 1.0f / sm;
        for (int c = 0; c < 4; c++) {
            int m = c * 64 + lane;
            if (m < 224) S[srow + m] = f2bf(e[c] * inv);
        }
    }
}

// LDS slot swizzle on the READ side. gload_lds writes LDS linearly; the
// matching permutation is applied to the GLOBAL source column slot
// (slot ^ (row>>1)&3), so LDS[row][s] holds global slot s^xr and the
// reader fetches global slot q at LDS[row][q^xr] == swz_off(row, q*8).
__device__ __forceinline__ int swz_off(int row, int kcElem) {
    return row * 32 + (kcElem ^ (((row >> 1) & 3) << 3));
}

// ---------------- NT-mode MFMA bf16 GEMM, 128x128 tile, BK=32 ----------------
// Mode-specialized K-loop (both variants hardware-proven r8/r9/r10):
//  LONG-K modes (0,3,4,5): 2-buffer + __syncthreads, 32 KB LDS, 4 blocks/CU.
//  SHORT-K modes (1,2; 2-7 K-steps): 3-buffer counted-vmcnt depth-2
//    pipeline, 48 KB LDS, 3 blocks/CU.
// MODE 0: qkv = lnw @ qkvT^T + bias              (bf16 out Cb)
// MODE 1: S = q [k | relT]^T per (window,head)   (bf16 out Cb, ld 256;
//          B rows 0..195 = k rows, 196..249 = relT rows — merged rel-bias GEMM)
// MODE 2: PV: P @ Vt^T -> qkvc q-slot (dead after mode 1)  (bf16, ld 2304)
// MODE 3: proj from qkvc q-slot — scatter; Cf[g] = x_fp32[g]+acc+bias (fp32)
// MODE 4: fc1 + bias + exact gelu                (bf16 out Cb)
// MODE 5: fc2 — Cf[idx] = xf[idx]+acc+bias       (fp32 d_out RMW)
template <int MODE>
__global__ __launch_bounds__(256, (MODE == 1 || MODE == 2) ? 3 : 4)
void gemm_nt(
    const u16* __restrict__ Aall, const u16* __restrict__ Ball,
    const float* __restrict__ bias, const float* xf,
    u16* __restrict__ Cb, float* Cf, int M, int row0)
{
    constexpr int BK = 32;
    constexpr bool DEEP = (MODE == 1 || MODE == 2);
    int N, K, lda, ldb;
    size_t aoff = 0, boff = 0, coff = 0;
    if constexpr (MODE == 0) { N = 2304; K = 768; lda = 768; ldb = 768; }
    else if constexpr (MODE == 1) {
        N = 250; K = 64; lda = 2304; ldb = 2304;
        int z = blockIdx.z;
        aoff = (size_t)(z / 12) * 196 * 2304 + (size_t)(z % 12) * 64;  // q
        boff = aoff + 768;                                             // k
        coff = (size_t)z * 196 * 256;
    } else if constexpr (MODE == 2) {
        N = 64; K = 224; lda = 256; ldb = 224;
        int z = blockIdx.z;
        aoff = (size_t)z * 196 * 256;                                  // P
        boff = (size_t)z * 64 * 224;                                   // V^T
        coff = (size_t)(z / 12) * 196 * 2304 + (size_t)(z % 12) * 64;  // q-slot
    } else if constexpr (MODE == 3) { N = 768; K = 768; lda = 2304; ldb = 768; }
    else if constexpr (MODE == 4) { N = 3072; K = 768; lda = 768; ldb = 768; }
    else { N = 768; K = 3072; lda = 3072; ldb = 3072; }

    // Staging buffers of 8192 u16 (As | Bs at +4096) each; epilogue reuses
    // [0, 8704 u16) as C staging.
    constexpr int NBUF = DEEP ? 3 : 2;
    __shared__ __align__(16) u16 smem[NBUF * 8192];

    int tid = threadIdx.x, wid = tid >> 6, lane = tid & 63;
    int quad = lane >> 4, l16 = lane & 15;

    // XCD-aware bijective block swizzle (m204) for single-z modes.
    int bx = blockIdx.x, by = blockIdx.y;
    if constexpr (MODE != 1 && MODE != 2) {
        int gX = gridDim.x;
        int nwg = gX * gridDim.y;
        int orig = by * gX + bx;
        int q = nwg >> 3, r = nwg & 7;
        int xcd = orig & 7, idx = orig >> 3;
        int wg = (xcd < r ? xcd * (q + 1) : r * (q + 1) + (xcd - r) * q) + idx;
        bx = wg % gX; by = wg / gX;
    }
    int m_tile = by * 128, n_tile = bx * 128;
    int wm0 = (wid >> 1) * 64, wn0 = (wid & 1) * 64;

    const u16* A = Aall + aoff;
    const u16* B = Ball + boff;
    const u16* rT = nullptr;
    if constexpr (MODE == 1) rT = (const u16*)xf;   // relT [64][64] bf16

    // staging: wave wid owns rows [wid*32, wid*32+32) of As and Bs.
    // 2 issues per operand; issue j: lane i -> lds row r0 + (i>>2), slot i&3.
    // global column slot pre-swizzled: (i&3) ^ ((row>>1)&3). rows clamped.
    const u16* gA[2]; const u16* gB[2];
    int loff[2];
    {
        int s = lane & 3, rofs = lane >> 2;
        for (int j = 0; j < 2; j++) {
            int r0 = wid * 32 + j * 16;
            int rr = r0 + rofs;
            int xr = (rr >> 1) & 3;
            int colo = ((s ^ xr) << 3);
            int am = m_tile + rr; if (am > M - 1) am = M - 1;
            int bn = n_tile + rr; if (bn > N - 1) bn = N - 1;
            gA[j] = A + (size_t)am * lda + colo;
            if constexpr (MODE == 1)
                gB[j] = (bn < 196) ? (B + (size_t)bn * 2304 + colo)
                                   : (rT + (size_t)(bn - 196) * 64 + colo);
            else
                gB[j] = B + (size_t)bn * ldb + colo;
            loff[j] = r0 * 32;
        }
    }

    f32x4_t acc[4][4];
    f32x4_t z4 = {0.f, 0.f, 0.f, 0.f};
    for (int mt = 0; mt < 4; mt++)
        for (int nt = 0; nt < 4; nt++) acc[mt][nt] = z4;

    if constexpr (!DEEP) {
        // --- r8-proven: 2-buffer, one __syncthreads per K-step ---
        for (int j = 0; j < 2; j++) {
            gld16(gA[j], smem + loff[j]);
            gld16(gB[j], smem + 4096 + loff[j]);
        }
        int cur = 0;
        for (int k0 = 0; k0 < K; k0 += BK) {
            __syncthreads();   // drains tile-k loads; waves done reading buf^1
            int boffc = cur << 13;
            if (k0 + BK < K) {
                int boffn = boffc ^ 8192;
                for (int j = 0; j < 2; j++) {
                    gld16(gA[j] + k0 + BK, smem + boffn + loff[j]);
                    gld16(gB[j] + k0 + BK, smem + boffn + 4096 + loff[j]);
                }
            }
            const u16* Ac = smem + boffc;
            const u16* Bc = smem + boffc + 4096;
            bf16x8_t af[4], bfv[4];
            for (int t = 0; t < 4; t++) {
                int ar = wm0 + t * 16 + l16;
                int br = wn0 + t * 16 + l16;
                af[t]  = *(const bf16x8_t*)&Ac[swz_off(ar, quad * 8)];
                bfv[t] = *(const bf16x8_t*)&Bc[swz_off(br, quad * 8)];
            }
            for (int mt = 0; mt < 4; mt++)
                for (int nt = 0; nt < 4; nt++)
                    acc[mt][nt] = __builtin_amdgcn_mfma_f32_16x16x32_bf16(
                        af[mt], bfv[nt], acc[mt][nt], 0, 0, 0);
            cur ^= 1;
        }
    } else {
        // --- r9-proven: 3-buffer counted-vmcnt depth-2 pipeline ---
        int nsteps = K / BK;   // 2..7 for DEEP modes
        for (int j = 0; j < 2; j++) {
            gld16(gA[j], smem + loff[j]);
            gld16(gB[j], smem + 4096 + loff[j]);
        }
        for (int j = 0; j < 2; j++) {
            gld16(gA[j] + BK, smem + 8192 + loff[j]);
            gld16(gB[j] + BK, smem + 12288 + loff[j]);
        }
        int cur = 0;
        for (int k = 0; k < nsteps; k++) {
            if (k + 1 < nsteps) {
                asm volatile("s_waitcnt vmcnt(4)" ::: "memory");
            } else {
                asm volatile("s_waitcnt vmcnt(0)" ::: "memory");
            }
            __builtin_amdgcn_sched_barrier(0);
            __builtin_amdgcn_s_barrier();
            __builtin_amdgcn_sched_barrier(0);
            if (k + 2 < nsteps) {
                int nb = cur + 2; if (nb >= 3) nb -= 3;
                u16* dst = smem + nb * 8192;
                int kn = (k + 2) * BK;
                for (int j = 0; j < 2; j++) {
                    gld16(gA[j] + kn, dst + loff[j]);
                    gld16(gB[j] + kn, dst + 4096 + loff[j]);
                }
            }
            const u16* Ac = smem + cur * 8192;
            const u16* Bc = Ac + 4096;
            bf16x8_t af[4], bfv[4];
            for (int t = 0; t < 4; t++) {
                int ar = wm0 + t * 16 + l16;
                int br = wn0 + t * 16 + l16;
                af[t]  = *(const bf16x8_t*)&Ac[swz_off(ar, quad * 8)];
                bfv[t] = *(const bf16x8_t*)&Bc[swz_off(br, quad * 8)];
            }
            for (int mt = 0; mt < 4; mt++)
                for (int nt = 0; nt < 4; nt++)
                    acc[mt][nt] = __builtin_amdgcn_mfma_f32_16x16x32_bf16(
                        af[mt], bfv[nt], acc[mt][nt], 0, 0, 0);
            cur++; if (cur >= 3) cur -= 3;
        }
    }

    // ---- epilogue (C/D frag layout: col=lane&15, row=quad*4+reg) ----
    if constexpr (MODE == 0 || MODE == 1 || MODE == 2 || MODE == 4) {
        u16* Cs = smem;   // [64][136] per half
        int ldc = (MODE == 0) ? 2304 : (MODE == 1) ? 256 : (MODE == 2) ? 2304 : 3072;
        int colmax = (MODE == 1) ? 256 : N;   // mode-1: junk cols 250..255 unread
        for (int half = 0; half < 2; half++) {
            __syncthreads();   // K-loop reads (or prev half) done
            if ((wm0 >> 6) == half) {
                for (int mt = 0; mt < 4; mt++) {
                    int rl = mt * 16 + quad * 4;
                    for (int nt = 0; nt < 4; nt++) {
                        int cl = wn0 + nt * 16 + l16;
                        int col = n_tile + cl;
                        for (int rg = 0; rg < 4; rg++) {
                            float v = acc[mt][nt][rg];
                            u16 o;
                            if constexpr (MODE == 0) o = f2bf(v + bias[col]);
                            else if constexpr (MODE == 4) {
                                float g = v + bias[col];
                                o = f2bf(0.5f * g * (1.0f + erff(g * 0.70710678118f)));
                            } else o = f2bf(v);
                            Cs[(rl + rg) * 136 + cl] = o;
                        }
                    }
                }
            }
            __syncthreads();
            for (int it = 0; it < 4; it++) {
                int chunk = tid + it * 256;
                int r = chunk >> 4, c8 = (chunk & 15) << 3;
                int grow = m_tile + half * 64 + r, gcol = n_tile + c8;
                if (grow >= M || gcol >= colmax) continue;
                *(uint4*)&Cb[coff + (size_t)grow * ldc + gcol] =
                    *(const uint4*)&Cs[r * 136 + c8];
            }
        }
    } else {
        // fp32 RMW modes (3, 5): four 32-row quarters through LDS
        float* Cfs = (float*)smem;   // [32][132]
        for (int q = 0; q < 4; q++) {
            __syncthreads();
            if ((wm0 >> 6) == (q >> 1)) {
                for (int mt2 = 0; mt2 < 2; mt2++) {
                    int mt = (q & 1) * 2 + mt2;
                    int rloc = mt2 * 16 + quad * 4;
                    for (int nt = 0; nt < 4; nt++) {
                        int cl = wn0 + nt * 16 + l16;
                        for (int rg = 0; rg < 4; rg++)
                            Cfs[(rloc + rg) * 132 + cl] = acc[mt][nt][rg];
                    }
                }
            }
            __syncthreads();
            for (int it = 0; it < 4; it++) {
                int chunk = tid + it * 256;
                int r = chunk >> 5, c4 = (chunk & 31) << 2;
                int grow = m_tile + q * 32 + r;
                int gcol = n_tile + c4;
                if (grow >= M || gcol >= N) continue;
                f32x4_t v4 = *(const f32x4_t*)&Cfs[r * 132 + c4];
                f32x4_t b4 = *(const f32x4_t*)&bias[gcol];
                if constexpr (MODE == 5) {
                    size_t idx = (size_t)(row0 + grow) * 768 + gcol;
                    f32x4_t x4 = *(const f32x4_t*)&xf[idx];
                    f32x4_t o4;
                    for (int j = 0; j < 4; j++) o4[j] = v4[j] + x4[j] + b4[j];
                    *(f32x4_t*)&Cf[idx] = o4;
                } else {
                    int wr = row0 + grow;
                    int wb2 = wr / 196, t2 = wr % 196;
                    int gh = ((wb2 % 25) / 5) * 14 + t2 / 14;
                    int gw = (wb2 % 5) * 14 + t2 % 14;
                    if (gh < 64 && gw < 64) {
                        size_t g = (size_t)(((wb2 / 25) * 64 + gh) * 64 + gw) * 768 + gcol;
                        f32x4_t x4 = *(const f32x4_t*)&xf[g];
                        f32x4_t o4;
                        for (int j = 0; j < 4; j++) o4[j] = v4[j] + x4[j] + b4[j];
                        *(f32x4_t*)&Cf[g] = o4;
                    }
                }
            }
        }
    }
}

extern "C" void kernel_launch(void* const* d_in, const int* in_sizes, int n_in,
                              void* d_out, int out_size, void* d_ws, size_t ws_size,
                              hipStream_t stream)
{
    (void)in_sizes; (void)n_in; (void)out_size;
    const float* x      = (const float*)d_in[0];
    const float* ln1_w  = (const float*)d_in[1];
    const float* ln1_b  = (const float*)d_in[2];
    const float* qkv_w  = (const float*)d_in[3];
    const float* qkv_b  = (const float*)d_in[4];
    const float* proj_w = (const float*)d_in[5];
    const float* proj_b = (const float*)d_in[6];
    const float* rel_h  = (const float*)d_in[7];
    const float* rel_w  = (const float*)d_in[8];
    const float* ln2_w  = (const float*)d_in[9];
    const float* ln2_b  = (const float*)d_in[10];
    const float* fc1_w  = (const float*)d_in[11];
    const float* fc1_b  = (const float*)d_in[12];
    const float* fc2_w  = (const float*)d_in[13];
    const float* fc2_b  = (const float*)d_in[14];

    // ---- ws layout: weights always at base, scratch above ----
    const size_t WT = 14155776ull + 8192ull;   // 13.5 MB weights + relT (8 KB)
    char* ws = (char*)d_ws;
    u16* qkvT  = (u16*)ws;
    u16* projT = qkvT + 2304 * 768;
    u16* fc1T  = projT + 768 * 768;
    u16* fc2T  = fc1T + 3072 * 768;
    u16* relT  = fc2T + 3072 * 768;            // [64][64] bf16
    char* scratch = ws + WT;
    size_t avail = (ws_size > WT) ? (ws_size - WT) : 0;

    // per-window: lnw 301056 + qkv 903168 + S 1204224 (ld 256) + vt 344064
    //           = 2752512  (attn output lives in qkvc's dead q-slot; no G2)
    // Wc capped at 50: attention working set 137 MB, L3-resident. Wc=100
    // (275 MB > 256 MB L3) measured: fc1 131->160 us cross-phase regression
    // (r11) — L3 thrash + deferred writeback bleed into the MLP window.
    const size_t perW = 2752512ull;
    static const int wc_cand[7] = {50, 25, 20, 10, 5, 2, 1};
    int Wc = 1;
    for (int i = 0; i < 7; i++) {
        if ((size_t)wc_cand[i] * perW <= avail) { Wc = wc_cand[i]; break; }
    }
    static const int rm_cand[8] = {16384, 8192, 4096, 2048, 1024, 512, 256, 128};
    int Rm = 128;
    for (int i = 0; i < 8; i++) {
        if ((size_t)rm_cand[i] * 7680ull <= avail) { Rm = rm_cand[i]; break; }
    }

    u16* lnwc  = (u16*)scratch;
    u16* qkvc  = (u16*)(scratch + (size_t)Wc * 301056ull);
    u16* Sc    = (u16*)(scratch + (size_t)Wc * 1204224ull);
    u16* vtc   = (u16*)(scratch + (size_t)Wc * 2408448ull);
    u16* hbuf  = (u16*)scratch;                               // MLP overlays
    u16* xn2c  = (u16*)(scratch + (size_t)Rm * 6144ull);
    float* dout = (float*)d_out;                              // x1 (fp32)

    transpose_wf<<<dim3(72, 24), 256, 0, stream>>>(qkv_w, qkvT, 768, 2304);
    transpose_wf<<<dim3(24, 24), 256, 0, stream>>>(proj_w, projT, 768, 768);
    transpose_wf<<<dim3(96, 24), 256, 0, stream>>>(fc1_w, fc1T, 768, 3072);
    transpose_wf<<<dim3(24, 96), 256, 0, stream>>>(fc2_w, fc2T, 3072, 768);
    build_relT<<<16, 256, 0, stream>>>(rel_h, rel_w, relT);

    int nch = 100 / Wc;
    int rows = Wc * 196;
    int gy = (rows + 127) / 128;
    for (int c = 0; c < nch; c++) {
        int r0 = c * rows;
        ln1_window<<<rows / 4, 256, 0, stream>>>(x, ln1_w, ln1_b, lnwc, r0);
        gemm_nt<0><<<dim3(18, gy), 256, 0, stream>>>(
            lnwc, qkvT, qkv_b, nullptr, qkvc, nullptr, rows, 0);
        gemm_nt<1><<<dim3(2, 2, Wc * 12), 256, 0, stream>>>(
            qkvc, qkvc, nullptr, (const float*)relT, Sc, nullptr, 196, 0);
        build_vt<<<Wc * 12, 256, 0, stream>>>(qkvc, vtc);
        softmax_rel2<<<dim3(7, Wc * 12), 256, 0, stream>>>(Sc);
        gemm_nt<2><<<dim3(1, 2, Wc * 12), 256, 0, stream>>>(
            Sc, vtc, nullptr, nullptr, qkvc, nullptr, 196, 0);
        gemm_nt<3><<<dim3(6, gy), 256, 0, stream>>>(
            qkvc, projT, proj_b, x, nullptr, dout, rows, r0);
    }

    int nm = 16384 / Rm;
    for (int c = 0; c < nm; c++) {
        int r0 = c * Rm;
        ln2_chunk<<<Rm / 4, 256, 0, stream>>>(dout + (size_t)r0 * 768, ln2_w, ln2_b, xn2c);
        gemm_nt<4><<<dim3(24, Rm / 128), 256, 0, stream>>>(
            xn2c, fc1T, fc1_b, nullptr, hbuf, nullptr, Rm, 0);
        gemm_nt<5><<<dim3(6, Rm / 128), 256, 0, stream>>>(
            hbuf, fc2T, fc2_b, dout, nullptr, dout, Rm, r0);
    }
}